// Round 2
// baseline (73.542 us; speedup 1.0000x reference)
//
#include <hip/hip_runtime.h>

#define NBATCH 4096
#define NSAMP  7
#define DIM    512

typedef float floatx4 __attribute__((ext_vector_type(4)));
typedef short short8  __attribute__((ext_vector_type(8)));

__device__ static __forceinline__ void load16_lds(const void* g, void* l) {
  __builtin_amdgcn_global_load_lds(
      (const __attribute__((address_space(1))) unsigned int*)g,
      (__attribute__((address_space(3))) unsigned int*)l, 16, 0, 0);
}

__device__ static __forceinline__ unsigned short f2bf_rne(float f) {
  union { float f; unsigned int u; } v; v.f = f;
  unsigned int u = v.u;
  u += 0x7FFFu + ((u >> 16) & 1u);
  return (unsigned short)(u >> 16);
}

// ---------------- preprocess: A[i,d] = mean_norm[i,d] + esum[i,d]*exp(ls[i,d])/7 ----
// grid (NBATCH, 2), 256 threads; each block = one row of one side.
__global__ __launch_bounds__(256) void prep_kernel(
    const float* __restrict__ qm, const float* __restrict__ qls, const float* __restrict__ eq,
    const float* __restrict__ tm, const float* __restrict__ tls, const float* __restrict__ ek,
    unsigned short* __restrict__ outA, unsigned short* __restrict__ outB)
{
  const int row  = blockIdx.x;
  const int side = blockIdx.y;
  const float* mean = side ? tm  : qm;
  const float* ls   = side ? tls : qls;
  const float* eps  = side ? ek  : eq;
  unsigned short* out = side ? outB : outA;

  const int t = threadIdx.x;  // handles float2 element t (512 floats = 256 float2)
  const float2* mean2 = (const float2*)(mean + (size_t)row * DIM);
  float2 m = mean2[t];
  float ss = m.x * m.x + m.y * m.y;
  #pragma unroll
  for (int off = 1; off < 64; off <<= 1) ss += __shfl_xor(ss, off);
  __shared__ float wss[4];
  if ((t & 63) == 0) wss[t >> 6] = ss;
  __syncthreads();
  const float tot = wss[0] + wss[1] + wss[2] + wss[3];
  const float rnorm = 1.0f / fmaxf(sqrtf(tot), 1e-12f);

  const float2* ls2 = (const float2*)(ls + (size_t)row * DIM);
  float2 l = ls2[t];
  const float e0 = __expf(l.x) * (1.0f / (float)NSAMP);
  const float e1 = __expf(l.y) * (1.0f / (float)NSAMP);

  const float2* eps2 = (const float2*)(eps + (size_t)row * (NSAMP * DIM));
  float sx = 0.f, sy = 0.f;
  #pragma unroll
  for (int n = 0; n < NSAMP; ++n) {
    float2 e = eps2[n * (DIM / 2) + t];
    sx += e.x; sy += e.y;
  }
  const float v0 = m.x * rnorm + sx * e0;
  const float v1 = m.y * rnorm + sy * e1;
  unsigned int packed = (unsigned int)f2bf_rne(v0) | ((unsigned int)f2bf_rne(v1) << 16);
  ((unsigned int*)out)[(size_t)row * (DIM / 2) + t] = packed;
}

// ---------------- fused GEMM + per-block LSE partials ----------------
// S = A * B^T (both [4096,512] bf16, K-contiguous). 128x128 tile, 4 waves (2x2),
// each wave 64x64 via 4x4 frags of mfma_f32_16x16x32_bf16. BK=32, single LDS buf.
// Per-row partial (max, sum) over this block's 128 columns -> partial[row][tileCol].
#define BM 128
#define BN 128
#define BK 32
#define NCB (NBATCH / BN)   // 32 column blocks

__global__ __launch_bounds__(256) void gemm_lse_kernel(
    const unsigned short* __restrict__ Abf, const unsigned short* __restrict__ Bbf,
    float2* __restrict__ partial, float* __restrict__ diag)
{
  __shared__ unsigned short sA[BM * BK];  // 8 KB
  __shared__ unsigned short sB[BN * BK];  // 8 KB
  __shared__ float2 part[BM][2];          // per-row (max,sum) per wave-column

  const int tid  = threadIdx.x;
  const int lane = tid & 63;
  const int wv   = tid >> 6;   // 0..3
  const int wr   = wv >> 1;    // wave row 0..1
  const int wc   = wv & 1;     // wave col 0..1

  const int tileRow = blockIdx.y;
  const int tileCol = blockIdx.x;

  floatx4 acc[4][4];
  #pragma unroll
  for (int m = 0; m < 4; ++m)
    #pragma unroll
    for (int n = 0; n < 4; ++n)
      acc[m][n] = (floatx4){0.f, 0.f, 0.f, 0.f};

  // staging: wave wv covers rows [wv*32, wv*32+32) of each 128x32 tile,
  // two 16-row (1024 B) chunks. global row stride = DIM*2 = 1024 B.
  const int srow   = wv * 32 + (lane >> 2);
  const int spiece = (lane & 3) * 16;  // 16B piece within the 64 B row

  const char* gA0 = (const char*)Abf + (size_t)(tileRow * BM + srow) * (DIM * 2) + spiece;
  const char* gA1 = gA0 + 16 * (DIM * 2);
  const char* gB0 = (const char*)Bbf + (size_t)(tileCol * BN + srow) * (DIM * 2) + spiece;
  const char* gB1 = gB0 + 16 * (DIM * 2);
  char* lA0 = (char*)sA + wv * 2048;
  char* lA1 = lA0 + 1024;
  char* lB0 = (char*)sB + wv * 2048;
  char* lB1 = lB0 + 1024;

  const int fr = lane & 15;   // fragment row/col index (0..15)
  const int kg = lane >> 4;   // k-chunk of 8 (0..3)

  for (int kt = 0; kt < DIM / BK; ++kt) {
    const size_t ko = (size_t)kt * (BK * 2);  // 64 B per K-step
    load16_lds(gA0 + ko, lA0);
    load16_lds(gA1 + ko, lA1);
    load16_lds(gB0 + ko, lB0);
    load16_lds(gB1 + ko, lB1);
    __syncthreads();  // drains vmcnt -> LDS tiles ready

    short8 af[4], bfr[4];
    #pragma unroll
    for (int m = 0; m < 4; ++m)
      af[m] = *(const short8*)&sA[(wr * 64 + m * 16 + fr) * BK + kg * 8];
    #pragma unroll
    for (int n = 0; n < 4; ++n)
      bfr[n] = *(const short8*)&sB[(wc * 64 + n * 16 + fr) * BK + kg * 8];

    #pragma unroll
    for (int m = 0; m < 4; ++m)
      #pragma unroll
      for (int n = 0; n < 4; ++n)
        acc[m][n] = __builtin_amdgcn_mfma_f32_16x16x32_bf16(af[m], bfr[n], acc[m][n], 0, 0, 0);

    __syncthreads();  // all waves done reading LDS before next stage
  }

  // epilogue: per-row (max, sum-of-exp) over this wave's 64 columns, then
  // merge the two wave-columns in LDS, write partial[row][tileCol].
  const int rowBase = tileRow * BM + wr * 64;
  const int colBase = tileCol * BN + wc * 64;
  #pragma unroll
  for (int m = 0; m < 4; ++m) {
    #pragma unroll
    for (int r = 0; r < 4; ++r) {
      const int gi = rowBase + m * 16 + kg * 4 + r;
      float lm = -3.0e38f;
      #pragma unroll
      for (int n = 0; n < 4; ++n) {
        const float c = acc[m][n][r];
        const int gj = colBase + n * 16 + fr;
        if (gi == gj) diag[gi] = c;   // exact f32 S[i,i]
        lm = fmaxf(lm, c);
      }
      #pragma unroll
      for (int off = 1; off < 16; off <<= 1) lm = fmaxf(lm, __shfl_xor(lm, off));
      float s = 0.f;
      #pragma unroll
      for (int n = 0; n < 4; ++n) s += __expf(acc[m][n][r] - lm);
      #pragma unroll
      for (int off = 1; off < 16; off <<= 1) s += __shfl_xor(s, off);
      if (fr == 0) part[wr * 64 + m * 16 + kg * 4 + r][wc] = make_float2(lm, s);
    }
  }
  __syncthreads();
  if (tid < BM) {
    const float2 p0 = part[tid][0];
    const float2 p1 = part[tid][1];
    const float M = fmaxf(p0.x, p1.x);
    const float S = p0.y * __expf(p0.x - M) + p1.y * __expf(p1.x - M);
    partial[(size_t)(tileRow * BM + tid) * NCB + tileCol] = make_float2(M, S);
  }
}

// ---------------- finalize 1: per-row LSE merge + per-block loss partial ----
__global__ __launch_bounds__(256) void finalize1_kernel(
    const float2* __restrict__ partial, const float* __restrict__ diag,
    float* __restrict__ blocksum)
{
  const int i = blockIdx.x * 256 + threadIdx.x;  // row
  const float2* p = partial + (size_t)i * NCB;
  float M = -3.0e38f;
  #pragma unroll 8
  for (int k = 0; k < NCB; ++k) M = fmaxf(M, p[k].x);
  float S = 0.f;
  #pragma unroll 8
  for (int k = 0; k < NCB; ++k) S += p[k].y * __expf(p[k].x - M);
  float v = M + logf(S) - diag[i];

  #pragma unroll
  for (int off = 1; off < 64; off <<= 1) v += __shfl_xor(v, off);
  __shared__ float wss[4];
  if ((threadIdx.x & 63) == 0) wss[threadIdx.x >> 6] = v;
  __syncthreads();
  if (threadIdx.x == 0)
    blocksum[blockIdx.x] = wss[0] + wss[1] + wss[2] + wss[3];
}

// ---------------- finalize 2: sum 16 block partials, divide ----------------
__global__ void finalize2_kernel(const float* __restrict__ blocksum, float* __restrict__ out)
{
  float s = 0.f;
  #pragma unroll
  for (int k = 0; k < 16; ++k) s += blocksum[k];
  out[0] = s * (1.0f / (float)NBATCH);
}

extern "C" void kernel_launch(void* const* d_in, const int* in_sizes, int n_in,
                              void* d_out, int out_size, void* d_ws, size_t ws_size,
                              hipStream_t stream) {
  const float* qm  = (const float*)d_in[0];
  const float* qls = (const float*)d_in[1];
  const float* tm  = (const float*)d_in[2];
  const float* tls = (const float*)d_in[3];
  const float* eq  = (const float*)d_in[4];
  const float* ek  = (const float*)d_in[5];
  float* out = (float*)d_out;

  char* ws = (char*)d_ws;
  unsigned short* Abf = (unsigned short*)ws;                        // 4 MB
  unsigned short* Bbf = (unsigned short*)(ws + (size_t)4194304);    // 4 MB
  float2* partial = (float2*)(ws + (size_t)8388608);                // 1 MB
  float*  diag    = (float*)(ws + (size_t)8388608 + 1048576);       // 16 KB
  float*  blocksum= (float*)(ws + (size_t)8388608 + 1048576 + 16384); // 64 B

  prep_kernel<<<dim3(NBATCH, 2), 256, 0, stream>>>(qm, qls, eq, tm, tls, ek, Abf, Bbf);
  gemm_lse_kernel<<<dim3(NBATCH / BN, NBATCH / BM), 256, 0, stream>>>(Abf, Bbf, partial, diag);
  finalize1_kernel<<<NBATCH / 256, 256, 0, stream>>>(partial, diag, blocksum);
  finalize2_kernel<<<1, 1, 0, stream>>>(blocksum, out);
}